// Round 4
// baseline (344.713 us; speedup 1.0000x reference)
//
#include <hip/hip_runtime.h>

#define NUM_BINS 256
#define HW 262144        // 512*512
#define NBATCH 64

// ---------------------------------------------------------------------------
// gray = clip(round(0.299*u8r + 0.587*u8g + 0.114*u8b), 0, 255)
// u8c  = clip(floor(xc*255), 0, 255)
// Bit-exact vs float32 reference: no FMA contraction, left-to-right
// association, rintf = round-half-to-even (jnp.round).
// ---------------------------------------------------------------------------
__device__ __forceinline__ int gray_px(float r, float g, float b) {
#pragma clang fp contract(off)
    float ur = fminf(fmaxf(floorf(r * 255.0f), 0.0f), 255.0f);
    float ug = fminf(fmaxf(floorf(g * 255.0f), 0.0f), 255.0f);
    float ub = fminf(fmaxf(floorf(b * 255.0f), 0.0f), 255.0f);
    float s = 0.299f * ur + 0.587f * ug + 0.114f * ub;   // (a+b)+c, no fma
    s = fminf(fmaxf(rintf(s), 0.0f), 255.0f);
    return (int)s;
}

// ---------------------------------------------------------------------------
// Kernel A: zero global histograms (ws is poisoned to 0xAA before every call)
// ---------------------------------------------------------------------------
__global__ void init_hist_k(unsigned int* __restrict__ hist) {
    hist[(blockIdx.x << 8) + threadIdx.x] = 0u;
}

// ---------------------------------------------------------------------------
// Kernel B: gray + per-batch histogram.
// grid = NBATCH * 64 blocks, 256 threads, 16 px/thread via 4x float4/channel.
// LDS-privatized histogram, one global atomic per bin per block.
// ---------------------------------------------------------------------------
__global__ void __launch_bounds__(256)
gray_hist_k(const float* __restrict__ x, unsigned char* __restrict__ gray,
            unsigned int* __restrict__ hist) {
    __shared__ unsigned int lh[NUM_BINS];
    const int t = threadIdx.x;
    lh[t] = 0u;
    __syncthreads();

    const int b     = blockIdx.x >> 6;   // /64
    const int chunk = blockIdx.x & 63;
    const size_t base = (size_t)b * 3 * HW;
    const float4* xr = (const float4*)(x + base);
    const float4* xg = (const float4*)(x + base + HW);
    const float4* xb = (const float4*)(x + base + 2 * HW);
    uchar4* gout = gray ? (uchar4*)(gray + (size_t)b * HW) : nullptr;

#pragma unroll
    for (int i = 0; i < 4; ++i) {
        const int vidx = (chunk << 10) + (i << 8) + t;   // float4 index in batch
        float4 r4 = xr[vidx];
        float4 g4 = xg[vidx];
        float4 b4 = xb[vidx];
        int g0 = gray_px(r4.x, g4.x, b4.x);
        int g1 = gray_px(r4.y, g4.y, b4.y);
        int g2 = gray_px(r4.z, g4.z, b4.z);
        int g3 = gray_px(r4.w, g4.w, b4.w);
        if (gout) gout[vidx] = make_uchar4((unsigned char)g0, (unsigned char)g1,
                                           (unsigned char)g2, (unsigned char)g3);
        atomicAdd(&lh[g0], 1u);
        atomicAdd(&lh[g1], 1u);
        atomicAdd(&lh[g2], 1u);
        atomicAdd(&lh[g3], 1u);
    }
    __syncthreads();
    atomicAdd(&hist[(b << 8) + t], lh[t]);
}

// ---------------------------------------------------------------------------
// Kernel C: Otsu per batch. 1 block, 64 lanes, lane b handles batch b.
// Float32 sequential cumsum semantics; first-occurrence argmax (strict >).
// ---------------------------------------------------------------------------
__global__ void __launch_bounds__(64)
otsu_k(const unsigned int* __restrict__ hist, int* __restrict__ thr) {
    const int b = threadIdx.x;
    const unsigned int* h = hist + (b << 8);
    const float invN = 1.0f / 262144.0f;   // exact: 2^-18

    float mu_t = 0.0f;
    for (int i = 0; i < NUM_BINS; ++i) {
#pragma clang fp contract(off)
        float p = (float)h[i] * invN;      // exact (== hist/262144.0f)
        mu_t += (float)i * p;
    }

    float omega = 0.0f, mu = 0.0f;
    float best = -3.0f;
    int bi = 0;
    for (int i = 0; i < NUM_BINS; ++i) {
#pragma clang fp contract(off)
        float p = (float)h[i] * invN;
        omega += p;
        mu += (float)i * p;
        float denom = omega * (1.0f - omega);
        float s;
        if (denom > 1e-12f) {
            float d = mu_t * omega - mu;
            s = (d * d) / fmaxf(denom, 1e-12f);
        } else {
            s = -1.0f;
        }
        if (s > best) { best = s; bi = i; }
    }
    thr[b] = bi;
}

// ---------------------------------------------------------------------------
// Kernel D: mask from staged gray bytes. 4 px/thread: uchar4 load, int4 store.
// Output is INT32 0/1 (harness reads d_out as int32 for the int64 reference).
// grid = NBATCH * 256 blocks, 256 threads.
// ---------------------------------------------------------------------------
__global__ void __launch_bounds__(256)
mask_gray_k(const unsigned char* __restrict__ gray, const int* __restrict__ thr,
            int* __restrict__ out) {
    const int b     = blockIdx.x >> 8;   // /256
    const int chunk = blockIdx.x & 255;
    const int vidx  = (chunk << 8) + threadIdx.x;  // 0..65535 uchar4 per batch
    const int th = thr[b];
    uchar4 g = ((const uchar4*)(gray + (size_t)b * HW))[vidx];
    int4 o;
    o.x = ((int)g.x > th) ? 1 : 0;
    o.y = ((int)g.y > th) ? 1 : 0;
    o.z = ((int)g.z > th) ? 1 : 0;
    o.w = ((int)g.w > th) ? 1 : 0;
    ((int4*)(out + (size_t)b * HW))[vidx] = o;
}

// ---------------------------------------------------------------------------
// Kernel D': fallback — recompute gray from x (used only if ws too small).
// ---------------------------------------------------------------------------
__global__ void __launch_bounds__(256)
mask_x_k(const float* __restrict__ x, const int* __restrict__ thr,
         int* __restrict__ out) {
    const int b     = blockIdx.x >> 8;
    const int chunk = blockIdx.x & 255;
    const int vidx  = (chunk << 8) + threadIdx.x;  // float4 index, 0..65535
    const int th = thr[b];
    const size_t base = (size_t)b * 3 * HW;
    float4 r4 = ((const float4*)(x + base))[vidx];
    float4 g4 = ((const float4*)(x + base + HW))[vidx];
    float4 b4 = ((const float4*)(x + base + 2 * HW))[vidx];
    int4 o;
    o.x = (gray_px(r4.x, g4.x, b4.x) > th) ? 1 : 0;
    o.y = (gray_px(r4.y, g4.y, b4.y) > th) ? 1 : 0;
    o.z = (gray_px(r4.z, g4.z, b4.z) > th) ? 1 : 0;
    o.w = (gray_px(r4.w, g4.w, b4.w) > th) ? 1 : 0;
    ((int4*)(out + (size_t)b * HW))[vidx] = o;
}

extern "C" void kernel_launch(void* const* d_in, const int* in_sizes, int n_in,
                              void* d_out, int out_size, void* d_ws, size_t ws_size,
                              hipStream_t stream) {
    const float* x = (const float*)d_in[0];
    int* out = (int*)d_out;
    unsigned char* ws = (unsigned char*)d_ws;

    const size_t grayBytes = (size_t)NBATCH * HW;          // 16 MiB
    const size_t histBytes = (size_t)NBATCH * NUM_BINS * 4; // 64 KiB
    const bool useGray = ws_size >= grayBytes + histBytes + 256;

    unsigned char* gray = useGray ? ws : nullptr;
    unsigned int* hist = (unsigned int*)(ws + (useGray ? grayBytes : 0));
    int* thr = (int*)((unsigned char*)hist + histBytes);

    init_hist_k<<<NBATCH, NUM_BINS, 0, stream>>>(hist);
    gray_hist_k<<<NBATCH * 64, 256, 0, stream>>>(x, gray, hist);
    otsu_k<<<1, 64, 0, stream>>>(hist, thr);
    if (useGray)
        mask_gray_k<<<NBATCH * 256, 256, 0, stream>>>(gray, thr, out);
    else
        mask_x_k<<<NBATCH * 256, 256, 0, stream>>>(x, thr, out);
}